// Round 1
// baseline (278.216 us; speedup 1.0000x reference)
//
#include <hip/hip_runtime.h>
#include <stdint.h>
#include <stddef.h>

#define NG 128
#define SEQ 512
#define CIN 64
#define HID 128
#define NROWS (NG*SEQ)   // 65536
#define KLEN 256

typedef __attribute__((ext_vector_type(8))) short v8s;
typedef __attribute__((ext_vector_type(4))) float v4f;
typedef unsigned short u16;

__device__ __forceinline__ float b2f(u16 u) {
    union { unsigned int i; float f; } v; v.i = ((unsigned int)u) << 16; return v.f;
}
__device__ __forceinline__ u16 f2b(float f) {
    unsigned int x = __float_as_uint(f);
    unsigned int r = (x + 0x7fffu + ((x >> 16) & 1u)) >> 16;
    return (u16)r;
}

// ---------------- prep: f32 -> bf16 copies of x and weights ----------------
__global__ void prep_kernel(const float* __restrict__ x, const float* __restrict__ Wp,
                            const float* __restrict__ Wi, const float* __restrict__ Wo,
                            u16* __restrict__ xbf, u16* __restrict__ Wpbf,
                            u16* __restrict__ Wibf, u16* __restrict__ Wobf) {
    int stride = gridDim.x * blockDim.x;
    int t0 = blockIdx.x * blockDim.x + threadIdx.x;
    for (int i = t0; i < NROWS * CIN; i += stride) xbf[i] = f2b(x[i]);
    for (int i = t0; i < 3 * 2 * HID * HID; i += stride) Wibf[i] = f2b(Wi[i]);
    for (int i = t0; i < 3 * HID * HID; i += stride) Wobf[i] = f2b(Wo[i]);
    for (int i = t0; i < HID * CIN; i += stride) Wpbf[i] = f2b(Wp[i]);
}

// ---------------- proj: h = x @ Wp^T + bp  (MFMA, no LDS) ----------------
__global__ __launch_bounds__(256) void proj_kernel(const u16* __restrict__ xbf,
                                                   const u16* __restrict__ Wp,
                                                   const float* __restrict__ bp,
                                                   u16* __restrict__ act) {
    const int wave = threadIdx.x >> 6, lane = threadIdx.x & 63;
    const int m0 = blockIdx.x * 64 + wave * 16;
    const int fr = lane & 15, kb = (lane >> 4) * 8;
    v4f acc[8];
#pragma unroll
    for (int i = 0; i < 8; i++) acc[i] = (v4f){0.f, 0.f, 0.f, 0.f};
#pragma unroll
    for (int ks = 0; ks < 2; ++ks) {
        v8s a = *(const v8s*)(xbf + (size_t)(m0 + fr) * CIN + ks * 32 + kb);
#pragma unroll
        for (int nt = 0; nt < 8; ++nt) {
            v8s b = *(const v8s*)(Wp + (size_t)(nt * 16 + fr) * CIN + ks * 32 + kb);
            acc[nt] = __builtin_amdgcn_mfma_f32_16x16x32_bf16(a, b, acc[nt], 0, 0, 0);
        }
    }
    const int rowb = m0 + ((lane >> 4) << 2);
#pragma unroll
    for (int nt = 0; nt < 8; ++nt) {
        int col = nt * 16 + fr;
        float bb = bp[col];
#pragma unroll
        for (int r = 0; r < 4; r++)
            act[(size_t)(rowb + r) * HID + col] = f2b(acc[nt][r] + bb);
    }
}

// ---------------- scan: causal exp-kernel conv via prefix scan ----------------
// y[l] = (q^{255-l}/S) * (P[l] - P[l-256]),  P[l] = sum_{m<=l} q^m x[m]
__global__ __launch_bounds__(128) void scan_kernel(const u16* __restrict__ act,
                                                   u16* __restrict__ y,
                                                   const float* __restrict__ log_tau, int d) {
    const int b = blockIdx.x, c = threadIdx.x;
    float tau = fmaxf(expf(log_tau[d * HID + c]), 0.001f);
    float q = expf(-1.0f / tau);
    float lq = -(1.0f / tau) * 1.44269504089f;   // log2(q)
    float S = (q < 0.9999999f) ? (1.0f - exp2f(256.0f * lq)) / (1.0f - q) : 256.0f;
    float invS = 1.0f / (S + 1e-8f);
    float qinv = exp2f(-lq);
    const u16* col = act + (size_t)b * (SEQ * HID) + c;
    u16* ycol = y + (size_t)b * (SEQ * HID) + c;
    float P = 0.f, Pd = 0.f;
    for (int t = 0; t < 32; ++t) {
        const int l0 = t * 16;
        float xv[16];
#pragma unroll
        for (int j = 0; j < 16; j++) xv[j] = b2f(col[(l0 + j) * HID]);
        float xd[16];
        if (l0 >= KLEN) {
#pragma unroll
            for (int j = 0; j < 16; j++) xd[j] = b2f(col[(l0 - KLEN + j) * HID]);
        }
        float sp = exp2f((float)l0 * lq);                    // q^l
        float w = exp2f((float)(255 - l0) * lq) * invS;      // q^{255-l}/S
        float spd = (l0 >= KLEN) ? exp2f((float)(l0 - KLEN) * lq) : 0.f;
#pragma unroll
        for (int j = 0; j < 16; j++) {
            P += sp * xv[j];
            float Pold = 0.f;
            if (l0 >= KLEN) { Pd += spd * xd[j]; Pold = Pd; spd *= q; }
            ycol[(l0 + j) * HID] = f2b(w * (P - Pold));
            sp *= q; w *= qinv;
        }
    }
}

// ---------------- fused MLP + residual + LayerNorm (MFMA) ----------------
__global__ __launch_bounds__(256) void mlp_kernel(const u16* __restrict__ y,
                                                  const u16* __restrict__ Win,
                                                  const u16* __restrict__ Wout,
                                                  const float* __restrict__ b_in,
                                                  const float* __restrict__ b_out,
                                                  const float* __restrict__ gamma,
                                                  const float* __restrict__ beta,
                                                  u16* __restrict__ actout) {
    __shared__ u16 ulds[64][136];
    const int wave = threadIdx.x >> 6, lane = threadIdx.x & 63;
    const int gm0 = blockIdx.x * 64;
    const int fr = lane & 15, kb = (lane >> 4) * 8;
    const int arow = gm0 + wave * 16 + fr;

    v4f acc[16];
#pragma unroll
    for (int i = 0; i < 16; i++) acc[i] = (v4f){0.f, 0.f, 0.f, 0.f};
#pragma unroll
    for (int ks = 0; ks < 4; ++ks) {
        v8s a = *(const v8s*)(y + (size_t)arow * HID + ks * 32 + kb);
#pragma unroll
        for (int nt = 0; nt < 16; ++nt) {
            v8s b = *(const v8s*)(Win + (size_t)(nt * 16 + fr) * HID + ks * 32 + kb);
            acc[nt] = __builtin_amdgcn_mfma_f32_16x16x32_bf16(a, b, acc[nt], 0, 0, 0);
        }
    }
    // GLU: u = a * sigmoid(g); write to LDS for GEMM2 A-operand re-layout
    const int lrow = wave * 16 + ((lane >> 4) << 2);
#pragma unroll
    for (int nt = 0; nt < 8; ++nt) {
        int col = nt * 16 + fr;
        float ba = b_in[col];
        float bg = b_in[HID + col];
#pragma unroll
        for (int r = 0; r < 4; r++) {
            float av = acc[nt][r] + ba;
            float gv = acc[nt + 8][r] + bg;
            float u = av * (1.0f / (1.0f + __expf(-gv)));
            ulds[lrow + r][col] = f2b(u);
        }
    }
    __syncthreads();

    v4f acc2[8];
#pragma unroll
    for (int i = 0; i < 8; i++) acc2[i] = (v4f){0.f, 0.f, 0.f, 0.f};
#pragma unroll
    for (int ks = 0; ks < 4; ++ks) {
        v8s a = *(const v8s*)(&ulds[wave * 16 + fr][ks * 32 + kb]);
#pragma unroll
        for (int nt = 0; nt < 8; ++nt) {
            v8s b = *(const v8s*)(Wout + (size_t)(nt * 16 + fr) * HID + ks * 32 + kb);
            acc2[nt] = __builtin_amdgcn_mfma_f32_16x16x32_bf16(a, b, acc2[nt], 0, 0, 0);
        }
    }
    // z = y2 + b_out + y (residual), then rowwise LN over 128 channels
    float z[8][4];
    float s1[4] = {0.f, 0.f, 0.f, 0.f}, s2[4] = {0.f, 0.f, 0.f, 0.f};
#pragma unroll
    for (int nt = 0; nt < 8; ++nt) {
        int col = nt * 16 + fr;
        float bo = b_out[col];
#pragma unroll
        for (int r = 0; r < 4; r++) {
            int grow = gm0 + lrow + r;
            float zz = acc2[nt][r] + bo + b2f(y[(size_t)grow * HID + col]);
            z[nt][r] = zz;
            s1[r] += zz; s2[r] += zz * zz;
        }
    }
#pragma unroll
    for (int m = 1; m < 16; m <<= 1) {
#pragma unroll
        for (int r = 0; r < 4; r++) {
            s1[r] += __shfl_xor(s1[r], m);
            s2[r] += __shfl_xor(s2[r], m);
        }
    }
    float mu[4], rstd[4];
#pragma unroll
    for (int r = 0; r < 4; r++) {
        mu[r] = s1[r] * (1.0f / 128.0f);
        float var = s2[r] * (1.0f / 128.0f) - mu[r] * mu[r];
        rstd[r] = rsqrtf(var + 1e-5f);
    }
#pragma unroll
    for (int nt = 0; nt < 8; ++nt) {
        int col = nt * 16 + fr;
        float g = gamma[col], bb = beta[col];
#pragma unroll
        for (int r = 0; r < 4; r++) {
            int grow = gm0 + lrow + r;
            actout[(size_t)grow * HID + col] = f2b((z[nt][r] - mu[r]) * rstd[r] * g + bb);
        }
    }
}

// ---------------- final mean over L ----------------
__global__ __launch_bounds__(512) void mean_kernel(const u16* __restrict__ act, float* __restrict__ out) {
    __shared__ float red[4][128];
    const int b = blockIdx.x;
    const int c = threadIdx.x & 127, lq = threadIdx.x >> 7;
    const u16* col = act + (size_t)b * (SEQ * HID) + (size_t)lq * 128 * HID + c;
    float s = 0.f;
    for (int t = 0; t < 16; ++t) {
        float v[8];
#pragma unroll
        for (int j = 0; j < 8; j++) v[j] = b2f(col[(t * 8 + j) * HID]);
#pragma unroll
        for (int j = 0; j < 8; j++) s += v[j];
    }
    red[lq][c] = s;
    __syncthreads();
    if (threadIdx.x < 128) {
        float tot = red[0][c] + red[1][c] + red[2][c] + red[3][c];
        out[b * HID + c] = tot * (1.0f / 512.0f);
    }
}

extern "C" void kernel_launch(void* const* d_in, const int* in_sizes, int n_in,
                              void* d_out, int out_size, void* d_ws, size_t ws_size,
                              hipStream_t stream) {
    const float* x       = (const float*)d_in[0];
    // d_in[1] = batch (unused by reference math)
    const float* Wp      = (const float*)d_in[2];
    const float* bp      = (const float*)d_in[3];
    const float* log_tau = (const float*)d_in[4];
    const float* Wi      = (const float*)d_in[5];
    const float* bi      = (const float*)d_in[6];
    const float* Wo      = (const float*)d_in[7];
    const float* bo      = (const float*)d_in[8];
    const float* gm      = (const float*)d_in[9];
    const float* bt      = (const float*)d_in[10];
    float* out = (float*)d_out;

    char* ws = (char*)d_ws;
    const size_t ACT_BYTES = (size_t)NROWS * HID * 2;       // 16 MB
    u16* actA = (u16*)(ws);
    u16* yB   = (u16*)(ws + ACT_BYTES);
    u16* xbf  = yB;  // alias: xbf dead before scan0 writes yB
    u16* Wibf = (u16*)(ws + 2 * ACT_BYTES);
    u16* Wobf = (u16*)(ws + 2 * ACT_BYTES + (size_t)3 * 2 * HID * HID * 2);
    u16* Wpbf = (u16*)(ws + 2 * ACT_BYTES + (size_t)3 * 2 * HID * HID * 2 + (size_t)3 * HID * HID * 2);

    prep_kernel<<<1024, 256, 0, stream>>>(x, Wp, Wi, Wo, xbf, Wpbf, Wibf, Wobf);
    proj_kernel<<<NROWS / 64, 256, 0, stream>>>(xbf, Wpbf, bp, actA);
    for (int d = 0; d < 3; ++d) {
        scan_kernel<<<NG, HID, 0, stream>>>(actA, yB, log_tau, d);
        mlp_kernel<<<NROWS / 64, 256, 0, stream>>>(yB,
            Wibf + (size_t)d * 2 * HID * HID, Wobf + (size_t)d * HID * HID,
            bi + d * 2 * HID, bo + d * HID, gm + d * HID, bt + d * HID, actA);
    }
    mean_kernel<<<NG, 512, 0, stream>>>(actA, out);
}

// Round 2
// 200.055 us; speedup vs baseline: 1.3907x; 1.3907x over previous
//
#include <hip/hip_runtime.h>
#include <stdint.h>
#include <stddef.h>

#define NG 128
#define SEQ 512
#define CIN 64
#define HID 128
#define NROWS (NG*SEQ)   // 65536
#define KLEN 256

typedef __attribute__((ext_vector_type(8))) short v8s;
typedef __attribute__((ext_vector_type(4))) float v4f;
typedef unsigned short u16;

__device__ __forceinline__ float b2f(u16 u) {
    union { unsigned int i; float f; } v; v.i = ((unsigned int)u) << 16; return v.f;
}
__device__ __forceinline__ u16 f2b(float f) {
    unsigned int x = __float_as_uint(f);
    unsigned int r = (x + 0x7fffu + ((x >> 16) & 1u)) >> 16;
    return (u16)r;
}

// ---------------- prep: f32 -> bf16 copies of weights only ----------------
__global__ void prep_kernel(const float* __restrict__ Wp, const float* __restrict__ Wi,
                            const float* __restrict__ Wo,
                            u16* __restrict__ Wpbf, u16* __restrict__ Wibf,
                            u16* __restrict__ Wobf) {
    int stride = gridDim.x * blockDim.x;
    int t0 = blockIdx.x * blockDim.x + threadIdx.x;
    for (int i = t0; i < 3 * 2 * HID * HID; i += stride) Wibf[i] = f2b(Wi[i]);
    for (int i = t0; i < 3 * HID * HID; i += stride) Wobf[i] = f2b(Wo[i]);
    for (int i = t0; i < HID * CIN; i += stride) Wpbf[i] = f2b(Wp[i]);
}

// ---------------- proj: h = x @ Wp^T + bp  (f32 x read + in-reg convert) ----------------
__global__ __launch_bounds__(256, 4) void proj_kernel(const float* __restrict__ x,
                                                      const u16* __restrict__ Wp,
                                                      const float* __restrict__ bp,
                                                      u16* __restrict__ act) {
    const int wave = threadIdx.x >> 6, lane = threadIdx.x & 63;
    const int fr = lane & 15, kgrp = lane >> 4, kb = kgrp * 8;
    const int m0 = blockIdx.x * 128 + wave * 32;

    v4f acc[2][8];
#pragma unroll
    for (int rt = 0; rt < 2; ++rt)
#pragma unroll
        for (int nt = 0; nt < 8; ++nt) acc[rt][nt] = (v4f){0.f, 0.f, 0.f, 0.f};

#pragma unroll
    for (int ks = 0; ks < 2; ++ks) {
        v8s a[2];
#pragma unroll
        for (int rt = 0; rt < 2; ++rt) {
            const float* ap = x + (size_t)(m0 + rt * 16 + fr) * CIN + ks * 32 + kb;
            float4 f0 = *(const float4*)ap;
            float4 f1 = *(const float4*)(ap + 4);
            v8s t;
            t[0] = (short)f2b(f0.x); t[1] = (short)f2b(f0.y);
            t[2] = (short)f2b(f0.z); t[3] = (short)f2b(f0.w);
            t[4] = (short)f2b(f1.x); t[5] = (short)f2b(f1.y);
            t[6] = (short)f2b(f1.z); t[7] = (short)f2b(f1.w);
            a[rt] = t;
        }
#pragma unroll
        for (int nt = 0; nt < 8; ++nt) {
            v8s b = *(const v8s*)(Wp + (size_t)(nt * 16 + fr) * CIN + ks * 32 + kb);
            acc[0][nt] = __builtin_amdgcn_mfma_f32_16x16x32_bf16(a[0], b, acc[0][nt], 0, 0, 0);
            acc[1][nt] = __builtin_amdgcn_mfma_f32_16x16x32_bf16(a[1], b, acc[1][nt], 0, 0, 0);
        }
    }
#pragma unroll
    for (int rt = 0; rt < 2; ++rt)
#pragma unroll
        for (int nt = 0; nt < 8; ++nt) {
            int col = nt * 16 + fr;
            float bb = bp[col];
#pragma unroll
            for (int r = 0; r < 4; ++r)
                act[(size_t)(m0 + rt * 16 + kgrp * 4 + r) * HID + col] = f2b(acc[rt][nt][r] + bb);
        }
}

// ---------------- scan: causal exp-kernel conv via prefix scan ----------------
__global__ __launch_bounds__(128) void scan_kernel(const u16* __restrict__ act,
                                                   u16* __restrict__ y,
                                                   const float* __restrict__ log_tau, int d) {
    const int b = blockIdx.x, c = threadIdx.x;
    float tau = fmaxf(expf(log_tau[d * HID + c]), 0.001f);
    float q = expf(-1.0f / tau);
    float lq = -(1.0f / tau) * 1.44269504089f;   // log2(q)
    float S = (q < 0.9999999f) ? (1.0f - exp2f(256.0f * lq)) / (1.0f - q) : 256.0f;
    float invS = 1.0f / (S + 1e-8f);
    float qinv = exp2f(-lq);
    const u16* col = act + (size_t)b * (SEQ * HID) + c;
    u16* ycol = y + (size_t)b * (SEQ * HID) + c;
    float P = 0.f, Pd = 0.f;
    for (int t = 0; t < 32; ++t) {
        const int l0 = t * 16;
        float xv[16];
#pragma unroll
        for (int j = 0; j < 16; j++) xv[j] = b2f(col[(l0 + j) * HID]);
        float xd[16];
        if (l0 >= KLEN) {
#pragma unroll
            for (int j = 0; j < 16; j++) xd[j] = b2f(col[(l0 - KLEN + j) * HID]);
        }
        float sp = exp2f((float)l0 * lq);
        float w = exp2f((float)(255 - l0) * lq) * invS;
        float spd = (l0 >= KLEN) ? exp2f((float)(l0 - KLEN) * lq) : 0.f;
#pragma unroll
        for (int j = 0; j < 16; j++) {
            P += sp * xv[j];
            float Pold = 0.f;
            if (l0 >= KLEN) { Pd += spd * xd[j]; Pold = Pd; spd *= q; }
            ycol[(l0 + j) * HID] = f2b(w * (P - Pold));
            sp *= q; w *= qinv;
        }
    }
}

// ---------------- fused MLP + residual + LayerNorm (weight-stationary MFMA) ----------------
__global__ __launch_bounds__(512, 4) void mlp_kernel(const u16* __restrict__ y,
                                                     const u16* __restrict__ Win,
                                                     const u16* __restrict__ Wout,
                                                     const float* __restrict__ b_in,
                                                     const float* __restrict__ b_out,
                                                     const float* __restrict__ gamma,
                                                     const float* __restrict__ beta,
                                                     u16* __restrict__ actout) {
    __shared__ u16 ylds[128 * 128];   // 32 KB, XOR-swizzled
    __shared__ u16 ulds[128 * 128];   // 32 KB, XOR-swizzled
    const int tid = threadIdx.x;
    const int wave = tid >> 6, lane = tid & 63;
    const int fr = lane & 15, kgrp = lane >> 4, kb = kgrp * 8;
    const int gm0 = blockIdx.x * 128;

    // weight-stationary B1 frags: a-cols block nt=wave, g-cols block nt=wave+8
    v8s b1a[4], b1g[4];
#pragma unroll
    for (int ks = 0; ks < 4; ++ks) {
        b1a[ks] = *(const v8s*)(Win + (size_t)(wave * 16 + fr) * HID + ks * 32 + kb);
        b1g[ks] = *(const v8s*)(Win + (size_t)((wave + 8) * 16 + fr) * HID + ks * 32 + kb);
    }
    const float ba = b_in[wave * 16 + fr];
    const float bg = b_in[HID + wave * 16 + fr];

    // stage y tile -> swizzled ylds (coalesced global read)
    {
        const int row = tid >> 2;
        const int cb0 = (tid & 3) * 64;           // byte col base
        const u16* src = y + (size_t)(gm0 + row) * HID + (tid & 3) * 32;
        char* dst = (char*)ylds + row * 256;
        const int sw = (row & 7) << 4;
#pragma unroll
        for (int j = 0; j < 4; ++j)
            *(v8s*)(dst + ((cb0 + j * 16) ^ sw)) = *(const v8s*)(src + j * 8);
    }
    __syncthreads();

    // GEMM1 (N-split, B in regs) + in-register GLU -> swizzled ulds
#pragma unroll
    for (int rt = 0; rt < 8; ++rt) {
        const int arow = rt * 16 + fr;
        const char* abase = (const char*)ylds + arow * 256;
        const int asw = (arow & 7) << 4;
        v8s af[4];
#pragma unroll
        for (int ks = 0; ks < 4; ++ks)
            af[ks] = *(const v8s*)(abase + ((ks * 64 + kgrp * 16) ^ asw));
        v4f a0 = (v4f){0.f, 0.f, 0.f, 0.f}, a1 = (v4f){0.f, 0.f, 0.f, 0.f};
#pragma unroll
        for (int ks = 0; ks < 4; ++ks) {
            a0 = __builtin_amdgcn_mfma_f32_16x16x32_bf16(af[ks], b1a[ks], a0, 0, 0, 0);
            a1 = __builtin_amdgcn_mfma_f32_16x16x32_bf16(af[ks], b1g[ks], a1, 0, 0, 0);
        }
        const int colb = (wave * 16 + fr) * 2;
#pragma unroll
        for (int r = 0; r < 4; ++r) {
            const int urow = rt * 16 + kgrp * 4 + r;
            float av = a0[r] + ba;
            float gv = a1[r] + bg;
            float u = av * (1.0f / (1.0f + __expf(-gv)));
            *(u16*)((char*)ulds + urow * 256 + (colb ^ ((urow & 7) << 4))) = f2b(u);
        }
    }
    __syncthreads();

    // GEMM2: wave handles rows [16*wave, 16*wave+16), A from ulds, B from L1
    v4f acc2[8];
#pragma unroll
    for (int i = 0; i < 8; ++i) acc2[i] = (v4f){0.f, 0.f, 0.f, 0.f};
    {
        const int arow = wave * 16 + fr;
        const char* abase = (const char*)ulds + arow * 256;
        const int asw = (arow & 7) << 4;
#pragma unroll
        for (int ks = 0; ks < 4; ++ks) {
            v8s af = *(const v8s*)(abase + ((ks * 64 + kgrp * 16) ^ asw));
#pragma unroll
            for (int nt = 0; nt < 8; ++nt) {
                v8s b = *(const v8s*)(Wout + (size_t)(nt * 16 + fr) * HID + ks * 32 + kb);
                acc2[nt] = __builtin_amdgcn_mfma_f32_16x16x32_bf16(af, b, acc2[nt], 0, 0, 0);
            }
        }
    }
    // residual (from ylds) + rowwise LN
    float s1[4] = {0.f, 0.f, 0.f, 0.f}, s2[4] = {0.f, 0.f, 0.f, 0.f};
#pragma unroll
    for (int nt = 0; nt < 8; ++nt) {
        const int colb = (nt * 16 + fr) * 2;
        float bo = b_out[nt * 16 + fr];
#pragma unroll
        for (int r = 0; r < 4; ++r) {
            const int row = wave * 16 + kgrp * 4 + r;
            float yv = b2f(*(const u16*)((const char*)ylds + row * 256 + (colb ^ ((row & 7) << 4))));
            float zz = acc2[nt][r] + bo + yv;
            acc2[nt][r] = zz;
            s1[r] += zz; s2[r] += zz * zz;
        }
    }
#pragma unroll
    for (int m = 1; m < 16; m <<= 1) {
#pragma unroll
        for (int r = 0; r < 4; r++) {
            s1[r] += __shfl_xor(s1[r], m);
            s2[r] += __shfl_xor(s2[r], m);
        }
    }
    float mu[4], rstd[4];
#pragma unroll
    for (int r = 0; r < 4; r++) {
        mu[r] = s1[r] * (1.0f / 128.0f);
        float var = s2[r] * (1.0f / 128.0f) - mu[r] * mu[r];
        rstd[r] = rsqrtf(var + 1e-5f);
    }
#pragma unroll
    for (int nt = 0; nt < 8; ++nt) {
        int col = nt * 16 + fr;
        float g = gamma[col], bb = beta[col];
#pragma unroll
        for (int r = 0; r < 4; r++) {
            int grow = gm0 + wave * 16 + kgrp * 4 + r;
            actout[(size_t)grow * HID + col] = f2b((acc2[nt][r] - mu[r]) * rstd[r] * g + bb);
        }
    }
}

// ---------------- final mean over L ----------------
__global__ __launch_bounds__(512) void mean_kernel(const u16* __restrict__ act, float* __restrict__ out) {
    __shared__ float red[4][128];
    const int b = blockIdx.x;
    const int c = threadIdx.x & 127, lq = threadIdx.x >> 7;
    const u16* col = act + (size_t)b * (SEQ * HID) + (size_t)lq * 128 * HID + c;
    float s = 0.f;
    for (int t = 0; t < 16; ++t) {
        float v[8];
#pragma unroll
        for (int j = 0; j < 8; j++) v[j] = b2f(col[(t * 8 + j) * HID]);
#pragma unroll
        for (int j = 0; j < 8; j++) s += v[j];
    }
    red[lq][c] = s;
    __syncthreads();
    if (threadIdx.x < 128) {
        float tot = red[0][c] + red[1][c] + red[2][c] + red[3][c];
        out[b * HID + c] = tot * (1.0f / 512.0f);
    }
}

extern "C" void kernel_launch(void* const* d_in, const int* in_sizes, int n_in,
                              void* d_out, int out_size, void* d_ws, size_t ws_size,
                              hipStream_t stream) {
    const float* x       = (const float*)d_in[0];
    const float* Wp      = (const float*)d_in[2];
    const float* bp      = (const float*)d_in[3];
    const float* log_tau = (const float*)d_in[4];
    const float* Wi      = (const float*)d_in[5];
    const float* bi      = (const float*)d_in[6];
    const float* Wo      = (const float*)d_in[7];
    const float* bo      = (const float*)d_in[8];
    const float* gm      = (const float*)d_in[9];
    const float* bt      = (const float*)d_in[10];
    float* out = (float*)d_out;

    char* ws = (char*)d_ws;
    const size_t ACT_BYTES = (size_t)NROWS * HID * 2;       // 16 MB
    u16* actA = (u16*)(ws);
    u16* yB   = (u16*)(ws + ACT_BYTES);
    u16* Wibf = (u16*)(ws + 2 * ACT_BYTES);
    u16* Wobf = (u16*)(ws + 2 * ACT_BYTES + (size_t)3 * 2 * HID * HID * 2);
    u16* Wpbf = (u16*)(ws + 2 * ACT_BYTES + (size_t)3 * 2 * HID * HID * 2 + (size_t)3 * HID * HID * 2);

    prep_kernel<<<128, 256, 0, stream>>>(Wp, Wi, Wo, Wpbf, Wibf, Wobf);
    proj_kernel<<<NROWS / 128, 256, 0, stream>>>(x, Wpbf, bp, actA);
    for (int d = 0; d < 3; ++d) {
        scan_kernel<<<NG, HID, 0, stream>>>(actA, yB, log_tau, d);
        mlp_kernel<<<NROWS / 128, 512, 0, stream>>>(yB,
            Wibf + (size_t)d * 2 * HID * HID, Wobf + (size_t)d * HID * HID,
            bi + d * 2 * HID, bo + d * HID, gm + d * HID, bt + d * HID, actA);
    }
    mean_kernel<<<NG, 512, 0, stream>>>(actA, out);
}

// Round 3
// 152.600 us; speedup vs baseline: 1.8232x; 1.3110x over previous
//
#include <hip/hip_runtime.h>
#include <stdint.h>
#include <stddef.h>

#define NG 128
#define SEQ 512
#define CIN 64
#define HID 128
#define NROWS (NG*SEQ)   // 65536
#define KLEN 256

typedef __attribute__((ext_vector_type(8))) short v8s;
typedef __attribute__((ext_vector_type(4))) float v4f;
typedef unsigned short u16;

__device__ __forceinline__ float b2f(u16 u) {
    union { unsigned int i; float f; } v; v.i = ((unsigned int)u) << 16; return v.f;
}
__device__ __forceinline__ u16 f2b(float f) {
    unsigned int x = __float_as_uint(f);
    unsigned int r = (x + 0x7fffu + ((x >> 16) & 1u)) >> 16;
    return (u16)r;
}

// ---------------- prep: f32 -> bf16 copies of weights only ----------------
__global__ void prep_kernel(const float* __restrict__ Wp, const float* __restrict__ Wi,
                            const float* __restrict__ Wo,
                            u16* __restrict__ Wpbf, u16* __restrict__ Wibf,
                            u16* __restrict__ Wobf) {
    int stride = gridDim.x * blockDim.x;
    int t0 = blockIdx.x * blockDim.x + threadIdx.x;
    for (int i = t0; i < 3 * 2 * HID * HID; i += stride) Wibf[i] = f2b(Wi[i]);
    for (int i = t0; i < 3 * HID * HID; i += stride) Wobf[i] = f2b(Wo[i]);
    for (int i = t0; i < HID * CIN; i += stride) Wpbf[i] = f2b(Wp[i]);
}

// ---------------- proj: h = x @ Wp^T + bp  (f32 x read + in-reg convert) ----------------
__global__ __launch_bounds__(256, 4) void proj_kernel(const float* __restrict__ x,
                                                      const u16* __restrict__ Wp,
                                                      const float* __restrict__ bp,
                                                      u16* __restrict__ act) {
    const int wave = threadIdx.x >> 6, lane = threadIdx.x & 63;
    const int fr = lane & 15, kgrp = lane >> 4, kb = kgrp * 8;
    const int m0 = blockIdx.x * 128 + wave * 32;

    v4f acc[2][8];
#pragma unroll
    for (int rt = 0; rt < 2; ++rt)
#pragma unroll
        for (int nt = 0; nt < 8; ++nt) acc[rt][nt] = (v4f){0.f, 0.f, 0.f, 0.f};

#pragma unroll
    for (int ks = 0; ks < 2; ++ks) {
        v8s a[2];
#pragma unroll
        for (int rt = 0; rt < 2; ++rt) {
            const float* ap = x + (size_t)(m0 + rt * 16 + fr) * CIN + ks * 32 + kb;
            float4 f0 = *(const float4*)ap;
            float4 f1 = *(const float4*)(ap + 4);
            v8s t;
            t[0] = (short)f2b(f0.x); t[1] = (short)f2b(f0.y);
            t[2] = (short)f2b(f0.z); t[3] = (short)f2b(f0.w);
            t[4] = (short)f2b(f1.x); t[5] = (short)f2b(f1.y);
            t[6] = (short)f2b(f1.z); t[7] = (short)f2b(f1.w);
            a[rt] = t;
        }
#pragma unroll
        for (int nt = 0; nt < 8; ++nt) {
            v8s b = *(const v8s*)(Wp + (size_t)(nt * 16 + fr) * CIN + ks * 32 + kb);
            acc[0][nt] = __builtin_amdgcn_mfma_f32_16x16x32_bf16(a[0], b, acc[0][nt], 0, 0, 0);
            acc[1][nt] = __builtin_amdgcn_mfma_f32_16x16x32_bf16(a[1], b, acc[1][nt], 0, 0, 0);
        }
    }
#pragma unroll
    for (int rt = 0; rt < 2; ++rt)
#pragma unroll
        for (int nt = 0; nt < 8; ++nt) {
            int col = nt * 16 + fr;
            float bb = bp[col];
#pragma unroll
            for (int r = 0; r < 4; ++r)
                act[(size_t)(m0 + rt * 16 + kgrp * 4 + r) * HID + col] = f2b(acc[rt][nt][r] + bb);
        }
}

// ---------------- scan v2: chunked parallel prefix scan ----------------
// Block = (graph, 64-channel half). 512 threads = (c in 64) x (tc in 8).
// Chunk = 64 timesteps. Phase1: per-chunk decayed sum T (global exponent).
// Phase2: LDS exclusive prefix -> P carry (s<tc) and Pd carry (s<tc-4).
// Phase3: recompute with carries; y[l] = (q^{255-l}/S)*(P[l]-P[l-256]).
__global__ __launch_bounds__(512) void scan_kernel(const u16* __restrict__ act,
                                                   u16* __restrict__ y,
                                                   const float* __restrict__ log_tau, int d) {
    __shared__ float Tlds[8][64];
    const int b = blockIdx.x >> 1;
    const int c63 = threadIdx.x & 63;
    const int c = ((blockIdx.x & 1) << 6) + c63;
    const int tc = threadIdx.x >> 6;          // 0..7
    const int l0 = tc * 64;

    float tau = fmaxf(expf(log_tau[d * HID + c]), 0.001f);
    float q = expf(-1.0f / tau);
    float lq = -(1.0f / tau) * 1.44269504089f;   // log2(q)
    float S = (q < 0.9999999f) ? (1.0f - exp2f(256.0f * lq)) / (1.0f - q) : 256.0f;
    float invS = 1.0f / (S + 1e-8f);
    float qinv = exp2f(-lq);

    const u16* col = act + (size_t)b * (SEQ * HID) + c;
    u16* ycol = y + (size_t)b * (SEQ * HID) + c;

    // ---- phase 1: chunk-local decayed sum (global exponent q^l) ----
    float T = 0.f;
    {
        float sp = exp2f((float)l0 * lq);
#pragma unroll
        for (int t16 = 0; t16 < 4; ++t16) {
            const int lb = l0 + t16 * 16;
            float xv[16];
#pragma unroll
            for (int j = 0; j < 16; ++j) xv[j] = b2f(col[(lb + j) * HID]);
#pragma unroll
            for (int j = 0; j < 16; ++j) { T += sp * xv[j]; sp *= q; }
        }
    }
    Tlds[tc][c63] = T;
    __syncthreads();

    // ---- phase 2: exclusive prefixes ----
    float Pin = 0.f, Pdin = 0.f;
#pragma unroll
    for (int s = 0; s < 8; ++s) {
        float Ts = Tlds[s][c63];
        if (s < tc) Pin += Ts;
        if (s < tc - 4) Pdin += Ts;
    }

    // ---- phase 3: rescan with carries, emit y ----
    float P = Pin, Pd = Pdin;
    float sp = exp2f((float)l0 * lq);
    float w = exp2f((float)(255 - l0) * lq) * invS;
    float spd = (tc >= 4) ? exp2f((float)(l0 - KLEN) * lq) : 0.f;
#pragma unroll
    for (int t16 = 0; t16 < 4; ++t16) {
        const int lb = l0 + t16 * 16;
        float xv[16], xd[16];
#pragma unroll
        for (int j = 0; j < 16; ++j) xv[j] = b2f(col[(lb + j) * HID]);
        if (tc >= 4) {
#pragma unroll
            for (int j = 0; j < 16; ++j) xd[j] = b2f(col[(lb - KLEN + j) * HID]);
        }
#pragma unroll
        for (int j = 0; j < 16; ++j) {
            P += sp * xv[j];
            float Pold = 0.f;
            if (tc >= 4) { Pd += spd * xd[j]; Pold = Pd; spd *= q; }
            ycol[(lb + j) * HID] = f2b(w * (P - Pold));
            sp *= q; w *= qinv;
        }
    }
}

// ---------------- fused MLP + residual + LayerNorm (weight-stationary MFMA) ----------------
__global__ __launch_bounds__(512, 4) void mlp_kernel(const u16* __restrict__ y,
                                                     const u16* __restrict__ Win,
                                                     const u16* __restrict__ Wout,
                                                     const float* __restrict__ b_in,
                                                     const float* __restrict__ b_out,
                                                     const float* __restrict__ gamma,
                                                     const float* __restrict__ beta,
                                                     u16* __restrict__ actout) {
    __shared__ u16 ylds[128 * 128];   // 32 KB, XOR-swizzled
    __shared__ u16 ulds[128 * 128];   // 32 KB, XOR-swizzled
    const int tid = threadIdx.x;
    const int wave = tid >> 6, lane = tid & 63;
    const int fr = lane & 15, kgrp = lane >> 4, kb = kgrp * 8;
    const int gm0 = blockIdx.x * 128;

    // weight-stationary B1 frags: a-cols block nt=wave, g-cols block nt=wave+8
    v8s b1a[4], b1g[4];
#pragma unroll
    for (int ks = 0; ks < 4; ++ks) {
        b1a[ks] = *(const v8s*)(Win + (size_t)(wave * 16 + fr) * HID + ks * 32 + kb);
        b1g[ks] = *(const v8s*)(Win + (size_t)((wave + 8) * 16 + fr) * HID + ks * 32 + kb);
    }
    const float ba = b_in[wave * 16 + fr];
    const float bg = b_in[HID + wave * 16 + fr];

    // stage y tile -> swizzled ylds (coalesced global read)
    {
        const int row = tid >> 2;
        const int cb0 = (tid & 3) * 64;           // byte col base
        const u16* src = y + (size_t)(gm0 + row) * HID + (tid & 3) * 32;
        char* dst = (char*)ylds + row * 256;
        const int sw = (row & 7) << 4;
#pragma unroll
        for (int j = 0; j < 4; ++j)
            *(v8s*)(dst + ((cb0 + j * 16) ^ sw)) = *(const v8s*)(src + j * 8);
    }
    __syncthreads();

    // GEMM1 (N-split, B in regs) + in-register GLU -> swizzled ulds
#pragma unroll
    for (int rt = 0; rt < 8; ++rt) {
        const int arow = rt * 16 + fr;
        const char* abase = (const char*)ylds + arow * 256;
        const int asw = (arow & 7) << 4;
        v8s af[4];
#pragma unroll
        for (int ks = 0; ks < 4; ++ks)
            af[ks] = *(const v8s*)(abase + ((ks * 64 + kgrp * 16) ^ asw));
        v4f a0 = (v4f){0.f, 0.f, 0.f, 0.f}, a1 = (v4f){0.f, 0.f, 0.f, 0.f};
#pragma unroll
        for (int ks = 0; ks < 4; ++ks) {
            a0 = __builtin_amdgcn_mfma_f32_16x16x32_bf16(af[ks], b1a[ks], a0, 0, 0, 0);
            a1 = __builtin_amdgcn_mfma_f32_16x16x32_bf16(af[ks], b1g[ks], a1, 0, 0, 0);
        }
        const int colb = (wave * 16 + fr) * 2;
#pragma unroll
        for (int r = 0; r < 4; ++r) {
            const int urow = rt * 16 + kgrp * 4 + r;
            float av = a0[r] + ba;
            float gv = a1[r] + bg;
            float u = av * (1.0f / (1.0f + __expf(-gv)));
            *(u16*)((char*)ulds + urow * 256 + (colb ^ ((urow & 7) << 4))) = f2b(u);
        }
    }
    __syncthreads();

    // GEMM2: wave handles rows [16*wave, 16*wave+16), A from ulds, B from L1
    v4f acc2[8];
#pragma unroll
    for (int i = 0; i < 8; ++i) acc2[i] = (v4f){0.f, 0.f, 0.f, 0.f};
    {
        const int arow = wave * 16 + fr;
        const char* abase = (const char*)ulds + arow * 256;
        const int asw = (arow & 7) << 4;
#pragma unroll
        for (int ks = 0; ks < 4; ++ks) {
            v8s af = *(const v8s*)(abase + ((ks * 64 + kgrp * 16) ^ asw));
#pragma unroll
            for (int nt = 0; nt < 8; ++nt) {
                v8s b = *(const v8s*)(Wout + (size_t)(nt * 16 + fr) * HID + ks * 32 + kb);
                acc2[nt] = __builtin_amdgcn_mfma_f32_16x16x32_bf16(af, b, acc2[nt], 0, 0, 0);
            }
        }
    }
    // residual (from ylds) + rowwise LN
    float s1[4] = {0.f, 0.f, 0.f, 0.f}, s2[4] = {0.f, 0.f, 0.f, 0.f};
#pragma unroll
    for (int nt = 0; nt < 8; ++nt) {
        const int colb = (nt * 16 + fr) * 2;
        float bo = b_out[nt * 16 + fr];
#pragma unroll
        for (int r = 0; r < 4; ++r) {
            const int row = wave * 16 + kgrp * 4 + r;
            float yv = b2f(*(const u16*)((const char*)ylds + row * 256 + (colb ^ ((row & 7) << 4))));
            float zz = acc2[nt][r] + bo + yv;
            acc2[nt][r] = zz;
            s1[r] += zz; s2[r] += zz * zz;
        }
    }
#pragma unroll
    for (int m = 1; m < 16; m <<= 1) {
#pragma unroll
        for (int r = 0; r < 4; r++) {
            s1[r] += __shfl_xor(s1[r], m);
            s2[r] += __shfl_xor(s2[r], m);
        }
    }
    float mu[4], rstd[4];
#pragma unroll
    for (int r = 0; r < 4; r++) {
        mu[r] = s1[r] * (1.0f / 128.0f);
        float var = s2[r] * (1.0f / 128.0f) - mu[r] * mu[r];
        rstd[r] = rsqrtf(var + 1e-5f);
    }
#pragma unroll
    for (int nt = 0; nt < 8; ++nt) {
        int col = nt * 16 + fr;
        float g = gamma[col], bb = beta[col];
#pragma unroll
        for (int r = 0; r < 4; r++) {
            int grow = gm0 + wave * 16 + kgrp * 4 + r;
            actout[(size_t)grow * HID + col] = f2b((acc2[nt][r] - mu[r]) * rstd[r] * g + bb);
        }
    }
}

// ---------------- final mean over L ----------------
__global__ __launch_bounds__(512) void mean_kernel(const u16* __restrict__ act, float* __restrict__ out) {
    __shared__ float red[4][128];
    const int b = blockIdx.x;
    const int c = threadIdx.x & 127, lq = threadIdx.x >> 7;
    const u16* col = act + (size_t)b * (SEQ * HID) + (size_t)lq * 128 * HID + c;
    float s = 0.f;
    for (int t = 0; t < 16; ++t) {
        float v[8];
#pragma unroll
        for (int j = 0; j < 8; j++) v[j] = b2f(col[(t * 8 + j) * HID]);
#pragma unroll
        for (int j = 0; j < 8; j++) s += v[j];
    }
    red[lq][c] = s;
    __syncthreads();
    if (threadIdx.x < 128) {
        float tot = red[0][c] + red[1][c] + red[2][c] + red[3][c];
        out[b * HID + c] = tot * (1.0f / 512.0f);
    }
}

extern "C" void kernel_launch(void* const* d_in, const int* in_sizes, int n_in,
                              void* d_out, int out_size, void* d_ws, size_t ws_size,
                              hipStream_t stream) {
    const float* x       = (const float*)d_in[0];
    const float* Wp      = (const float*)d_in[2];
    const float* bp      = (const float*)d_in[3];
    const float* log_tau = (const float*)d_in[4];
    const float* Wi      = (const float*)d_in[5];
    const float* bi      = (const float*)d_in[6];
    const float* Wo      = (const float*)d_in[7];
    const float* bo      = (const float*)d_in[8];
    const float* gm      = (const float*)d_in[9];
    const float* bt      = (const float*)d_in[10];
    float* out = (float*)d_out;

    char* ws = (char*)d_ws;
    const size_t ACT_BYTES = (size_t)NROWS * HID * 2;       // 16 MB
    u16* actA = (u16*)(ws);
    u16* yB   = (u16*)(ws + ACT_BYTES);
    u16* Wibf = (u16*)(ws + 2 * ACT_BYTES);
    u16* Wobf = (u16*)(ws + 2 * ACT_BYTES + (size_t)3 * 2 * HID * HID * 2);
    u16* Wpbf = (u16*)(ws + 2 * ACT_BYTES + (size_t)3 * 2 * HID * HID * 2 + (size_t)3 * HID * HID * 2);

    prep_kernel<<<128, 256, 0, stream>>>(Wp, Wi, Wo, Wpbf, Wibf, Wobf);
    proj_kernel<<<NROWS / 128, 256, 0, stream>>>(x, Wpbf, bp, actA);
    for (int d = 0; d < 3; ++d) {
        scan_kernel<<<NG * 2, 512, 0, stream>>>(actA, yB, log_tau, d);
        mlp_kernel<<<NROWS / 128, 512, 0, stream>>>(yB,
            Wibf + (size_t)d * 2 * HID * HID, Wobf + (size_t)d * HID * HID,
            bi + d * 2 * HID, bo + d * HID, gm + d * HID, bt + d * HID, actA);
    }
    mean_kernel<<<NG, 512, 0, stream>>>(actA, out);
}

// Round 4
// 146.629 us; speedup vs baseline: 1.8974x; 1.0407x over previous
//
#include <hip/hip_runtime.h>
#include <stdint.h>
#include <stddef.h>

#define NG 128
#define SEQ 512
#define CIN 64
#define HID 128
#define NROWS (NG*SEQ)   // 65536
#define KLEN 256

typedef __attribute__((ext_vector_type(8))) short v8s;
typedef __attribute__((ext_vector_type(4))) short v4s;
typedef __attribute__((ext_vector_type(4))) float v4f;
typedef unsigned short u16;

__device__ __forceinline__ float b2f(u16 u) {
    union { unsigned int i; float f; } v; v.i = ((unsigned int)u) << 16; return v.f;
}
__device__ __forceinline__ u16 f2b(float f) {
    unsigned int x = __float_as_uint(f);
    unsigned int r = (x + 0x7fffu + ((x >> 16) & 1u)) >> 16;
    return (u16)r;
}

// ---------------- prep: f32 -> bf16 copies of weights only ----------------
__global__ void prep_kernel(const float* __restrict__ Wp, const float* __restrict__ Wi,
                            const float* __restrict__ Wo,
                            u16* __restrict__ Wpbf, u16* __restrict__ Wibf,
                            u16* __restrict__ Wobf) {
    int stride = gridDim.x * blockDim.x;
    int t0 = blockIdx.x * blockDim.x + threadIdx.x;
    for (int i = t0; i < 3 * 2 * HID * HID; i += stride) Wibf[i] = f2b(Wi[i]);
    for (int i = t0; i < 3 * HID * HID; i += stride) Wobf[i] = f2b(Wo[i]);
    for (int i = t0; i < HID * CIN; i += stride) Wpbf[i] = f2b(Wp[i]);
}

// ---------------- proj: h = x @ Wp^T + bp -> actT[g][c][l] (transposed) ----------------
__global__ __launch_bounds__(256, 4) void proj_kernel(const float* __restrict__ x,
                                                      const u16* __restrict__ Wp,
                                                      const float* __restrict__ bp,
                                                      u16* __restrict__ actT) {
    const int wave = threadIdx.x >> 6, lane = threadIdx.x & 63;
    const int fr = lane & 15, kgrp = lane >> 4, kb = kgrp * 8;
    const int m0 = blockIdx.x * 128 + wave * 32;
    const int g = blockIdx.x >> 2;
    const int lloc0 = (blockIdx.x & 3) * 128 + wave * 32;

    v4f acc[2][8];
#pragma unroll
    for (int rt = 0; rt < 2; ++rt)
#pragma unroll
        for (int nt = 0; nt < 8; ++nt) acc[rt][nt] = (v4f){0.f, 0.f, 0.f, 0.f};

#pragma unroll
    for (int ks = 0; ks < 2; ++ks) {
        v8s a[2];
#pragma unroll
        for (int rt = 0; rt < 2; ++rt) {
            const float* ap = x + (size_t)(m0 + rt * 16 + fr) * CIN + ks * 32 + kb;
            float4 f0 = *(const float4*)ap;
            float4 f1 = *(const float4*)(ap + 4);
            v8s t;
            t[0] = (short)f2b(f0.x); t[1] = (short)f2b(f0.y);
            t[2] = (short)f2b(f0.z); t[3] = (short)f2b(f0.w);
            t[4] = (short)f2b(f1.x); t[5] = (short)f2b(f1.y);
            t[6] = (short)f2b(f1.z); t[7] = (short)f2b(f1.w);
            a[rt] = t;
        }
#pragma unroll
        for (int nt = 0; nt < 8; ++nt) {
            v8s b = *(const v8s*)(Wp + (size_t)(nt * 16 + fr) * CIN + ks * 32 + kb);
            acc[0][nt] = __builtin_amdgcn_mfma_f32_16x16x32_bf16(a[0], b, acc[0][nt], 0, 0, 0);
            acc[1][nt] = __builtin_amdgcn_mfma_f32_16x16x32_bf16(a[1], b, acc[1][nt], 0, 0, 0);
        }
    }
#pragma unroll
    for (int rt = 0; rt < 2; ++rt)
#pragma unroll
        for (int nt = 0; nt < 8; ++nt) {
            int col = nt * 16 + fr;
            float bb = bp[col];
            v4s pk;
#pragma unroll
            for (int r = 0; r < 4; ++r) pk[r] = (short)f2b(acc[rt][nt][r] + bb);
            *(v4s*)(actT + ((size_t)g * HID + col) * SEQ + lloc0 + rt * 16 + kgrp * 4) = pk;
        }
}

// ---------------- chunkh: half-chunk decayed sums H[g][s][c], s in [0,16) ----------------
__global__ __launch_bounds__(512) void chunkh_kernel(const u16* __restrict__ actT,
                                                     float* __restrict__ H,
                                                     const float* __restrict__ log_tau, int d) {
    const int g = blockIdx.x >> 2, qt = blockIdx.x & 3;
    const int c = threadIdx.x & 127, sc = threadIdx.x >> 7;   // sc 0..3
    const int s = qt * 4 + sc;                                 // 0..15
    const int l0 = s * 32;
    float tau = fmaxf(expf(log_tau[d * HID + c]), 0.001f);
    float q = expf(-1.0f / tau);
    float lq = -(1.0f / tau) * 1.44269504089f;
    const u16* xc = actT + ((size_t)g * HID + c) * SEQ + l0;
    float sp = exp2f((float)l0 * lq);
    float acc = 0.f;
#pragma unroll
    for (int v = 0; v < 4; ++v) {
        v8s xv = *(const v8s*)(xc + v * 8);
#pragma unroll
        for (int j = 0; j < 8; ++j) { acc += sp * b2f((u16)xv[j]); sp *= q; }
    }
    H[(size_t)g * 2048 + s * 128 + c] = acc;
}

// ---------------- fused: scan-finish -> ylds -> GEMM1/GLU -> GEMM2 -> LN -> actT ----------------
__global__ __launch_bounds__(512, 4) void fused_kernel(const u16* __restrict__ actT,
                                                       const float* __restrict__ H,
                                                       const u16* __restrict__ Win,
                                                       const u16* __restrict__ Wout,
                                                       const float* __restrict__ b_in,
                                                       const float* __restrict__ b_out,
                                                       const float* __restrict__ gamma,
                                                       const float* __restrict__ beta,
                                                       const float* __restrict__ log_tau, int d,
                                                       u16* __restrict__ actTout) {
    __shared__ u16 ylds[128 * 128];   // 32 KB, XOR-swizzled, bf16 y (tile-local rows)
    __shared__ u16 ulds[128 * 128];   // 32 KB, XOR-swizzled
    const int tid = threadIdx.x;
    const int g = blockIdx.x >> 2, tile = blockIdx.x & 3;
    const int r0 = tile * 128;

    // ---- scan phase: thread (c, sc) produces y rows [r0+sc*32, +32) for channel c ----
    {
        const int c = tid & 127, sc = tid >> 7;
        const int l0 = r0 + sc * 32;
        float tau = fmaxf(expf(log_tau[d * HID + c]), 0.001f);
        float q = expf(-1.0f / tau);
        float lq = -(1.0f / tau) * 1.44269504089f;
        float S = (q < 0.9999999f) ? (1.0f - exp2f(256.0f * lq)) / (1.0f - q) : 256.0f;
        float invS = 1.0f / (S + 1e-8f);
        float qinv = exp2f(-lq);
        const float* Hg = H + (size_t)g * 2048;
        const int s0 = l0 >> 5;
        float Pin = 0.f, Pdin = 0.f;
#pragma unroll
        for (int s = 0; s < 16; ++s) {
            float hv = Hg[s * 128 + c];
            if (s < s0) Pin += hv;
            if (s < s0 - 8) Pdin += hv;
        }
        const u16* xc = actT + ((size_t)g * HID + c) * SEQ;
        float P = Pin, Pd = Pdin;
        float sp = exp2f((float)l0 * lq);
        float w = exp2f((float)(255 - l0) * lq) * invS;
        const bool hasd = (r0 >= 256);          // block-uniform
        float spd = hasd ? exp2f((float)(l0 - KLEN) * lq) : 0.f;
#pragma unroll
        for (int v = 0; v < 4; ++v) {
            v8s xv = *(const v8s*)(xc + l0 + v * 8);
            v8s xd = {};
            if (hasd) xd = *(const v8s*)(xc + l0 - KLEN + v * 8);
#pragma unroll
            for (int j = 0; j < 8; ++j) {
                P += sp * b2f((u16)xv[j]);
                float Pold = 0.f;
                if (hasd) { Pd += spd * b2f((u16)xd[j]); Pold = Pd; spd *= q; }
                const int lt = sc * 32 + v * 8 + j;
                *(u16*)((char*)ylds + lt * 256 + ((2 * c) ^ ((lt & 7) << 4))) = f2b(w * (P - Pold));
                sp *= q; w *= qinv;
            }
        }
    }
    __syncthreads();

    const int wave = tid >> 6, lane = tid & 63;
    const int fr = lane & 15, kgrp = lane >> 4, kb = kgrp * 8;

    // weight-stationary B1 frags: a-cols block nt=wave, g-cols block nt=wave+8
    v8s b1a[4], b1g[4];
#pragma unroll
    for (int ks = 0; ks < 4; ++ks) {
        b1a[ks] = *(const v8s*)(Win + (size_t)(wave * 16 + fr) * HID + ks * 32 + kb);
        b1g[ks] = *(const v8s*)(Win + (size_t)((wave + 8) * 16 + fr) * HID + ks * 32 + kb);
    }
    const float ba = b_in[wave * 16 + fr];
    const float bg = b_in[HID + wave * 16 + fr];

    // GEMM1 (N-split, B in regs) + in-register GLU -> swizzled ulds
#pragma unroll
    for (int rt = 0; rt < 8; ++rt) {
        const int arow = rt * 16 + fr;
        const char* abase = (const char*)ylds + arow * 256;
        const int asw = (arow & 7) << 4;
        v8s af[4];
#pragma unroll
        for (int ks = 0; ks < 4; ++ks)
            af[ks] = *(const v8s*)(abase + ((ks * 64 + kgrp * 16) ^ asw));
        v4f a0 = (v4f){0.f, 0.f, 0.f, 0.f}, a1 = (v4f){0.f, 0.f, 0.f, 0.f};
#pragma unroll
        for (int ks = 0; ks < 4; ++ks) {
            a0 = __builtin_amdgcn_mfma_f32_16x16x32_bf16(af[ks], b1a[ks], a0, 0, 0, 0);
            a1 = __builtin_amdgcn_mfma_f32_16x16x32_bf16(af[ks], b1g[ks], a1, 0, 0, 0);
        }
        const int colb = (wave * 16 + fr) * 2;
#pragma unroll
        for (int r = 0; r < 4; ++r) {
            const int urow = rt * 16 + kgrp * 4 + r;
            float av = a0[r] + ba;
            float gv = a1[r] + bg;
            float u = av * (1.0f / (1.0f + __expf(-gv)));
            *(u16*)((char*)ulds + urow * 256 + (colb ^ ((urow & 7) << 4))) = f2b(u);
        }
    }
    __syncthreads();

    // GEMM2: wave handles rows [16*wave, +16), A from ulds, B from L1
    v4f acc2[8];
#pragma unroll
    for (int i = 0; i < 8; ++i) acc2[i] = (v4f){0.f, 0.f, 0.f, 0.f};
    {
        const int arow = wave * 16 + fr;
        const char* abase = (const char*)ulds + arow * 256;
        const int asw = (arow & 7) << 4;
#pragma unroll
        for (int ks = 0; ks < 4; ++ks) {
            v8s af = *(const v8s*)(abase + ((ks * 64 + kgrp * 16) ^ asw));
#pragma unroll
            for (int nt = 0; nt < 8; ++nt) {
                v8s b = *(const v8s*)(Wout + (size_t)(nt * 16 + fr) * HID + ks * 32 + kb);
                acc2[nt] = __builtin_amdgcn_mfma_f32_16x16x32_bf16(af, b, acc2[nt], 0, 0, 0);
            }
        }
    }
    // residual (from ylds) + rowwise LN
    float s1[4] = {0.f, 0.f, 0.f, 0.f}, s2[4] = {0.f, 0.f, 0.f, 0.f};
#pragma unroll
    for (int nt = 0; nt < 8; ++nt) {
        const int colb = (nt * 16 + fr) * 2;
        float bo = b_out[nt * 16 + fr];
#pragma unroll
        for (int r = 0; r < 4; ++r) {
            const int row = wave * 16 + kgrp * 4 + r;
            float yv = b2f(*(const u16*)((const char*)ylds + row * 256 + (colb ^ ((row & 7) << 4))));
            float zz = acc2[nt][r] + bo + yv;
            acc2[nt][r] = zz;
            s1[r] += zz; s2[r] += zz * zz;
        }
    }
#pragma unroll
    for (int m = 1; m < 16; m <<= 1) {
#pragma unroll
        for (int r = 0; r < 4; r++) {
            s1[r] += __shfl_xor(s1[r], m);
            s2[r] += __shfl_xor(s2[r], m);
        }
    }
    float mu[4], rstd[4];
#pragma unroll
    for (int r = 0; r < 4; r++) {
        mu[r] = s1[r] * (1.0f / 128.0f);
        float var = s2[r] * (1.0f / 128.0f) - mu[r] * mu[r];
        rstd[r] = rsqrtf(var + 1e-5f);
    }
    // epilogue: transposed packed store (4 consecutive rows per lane -> 8B)
    const int lbase = r0 + wave * 16 + kgrp * 4;
#pragma unroll
    for (int nt = 0; nt < 8; ++nt) {
        int col = nt * 16 + fr;
        float gmv = gamma[col], bb = beta[col];
        v4s pk;
#pragma unroll
        for (int r = 0; r < 4; r++)
            pk[r] = (short)f2b((acc2[nt][r] - mu[r]) * rstd[r] * gmv + bb);
        *(v4s*)(actTout + ((size_t)g * HID + col) * SEQ + lbase) = pk;
    }
}

// ---------------- final mean over L (contiguous actT reads) ----------------
__global__ __launch_bounds__(512) void mean_kernel(const u16* __restrict__ actT, float* __restrict__ out) {
    __shared__ float red[4][128];
    const int g = blockIdx.x;
    const int c = threadIdx.x & 127, q4 = threadIdx.x >> 7;
    const u16* xc = actT + ((size_t)g * HID + c) * SEQ + q4 * 128;
    float s = 0.f;
#pragma unroll
    for (int v = 0; v < 16; ++v) {
        v8s x = *(const v8s*)(xc + v * 8);
#pragma unroll
        for (int j = 0; j < 8; ++j) s += b2f((u16)x[j]);
    }
    red[q4][c] = s;
    __syncthreads();
    if (threadIdx.x < 128) {
        float tot = red[0][c] + red[1][c] + red[2][c] + red[3][c];
        out[g * HID + c] = tot * (1.0f / 512.0f);
    }
}

extern "C" void kernel_launch(void* const* d_in, const int* in_sizes, int n_in,
                              void* d_out, int out_size, void* d_ws, size_t ws_size,
                              hipStream_t stream) {
    const float* x       = (const float*)d_in[0];
    const float* Wp      = (const float*)d_in[2];
    const float* bp      = (const float*)d_in[3];
    const float* log_tau = (const float*)d_in[4];
    const float* Wi      = (const float*)d_in[5];
    const float* bi      = (const float*)d_in[6];
    const float* Wo      = (const float*)d_in[7];
    const float* bo      = (const float*)d_in[8];
    const float* gm      = (const float*)d_in[9];
    const float* bt      = (const float*)d_in[10];
    float* out = (float*)d_out;

    char* ws = (char*)d_ws;
    const size_t ACT_BYTES = (size_t)NROWS * HID * 2;       // 16 MB
    u16* actA  = (u16*)(ws);
    u16* actB  = (u16*)(ws + ACT_BYTES);
    float* Hbuf = (float*)(ws + 2 * ACT_BYTES);              // 1 MB
    char* wbase = ws + 2 * ACT_BYTES + (size_t)NG * 2048 * 4;
    u16* Wibf = (u16*)(wbase);
    u16* Wobf = (u16*)(wbase + (size_t)3 * 2 * HID * HID * 2);
    u16* Wpbf = (u16*)(wbase + (size_t)3 * 2 * HID * HID * 2 + (size_t)3 * HID * HID * 2);

    prep_kernel<<<128, 256, 0, stream>>>(Wp, Wi, Wo, Wpbf, Wibf, Wobf);
    proj_kernel<<<NROWS / 128, 256, 0, stream>>>(x, Wpbf, bp, actA);

    u16* cur = actA, *nxt = actB;
    for (int d = 0; d < 3; ++d) {
        chunkh_kernel<<<NG * 4, 512, 0, stream>>>(cur, Hbuf, log_tau, d);
        fused_kernel<<<NG * 4, 512, 0, stream>>>(cur, Hbuf,
            Wibf + (size_t)d * 2 * HID * HID, Wobf + (size_t)d * HID * HID,
            bi + d * 2 * HID, bo + d * HID, gm + d * HID, bt + d * HID,
            log_tau, d, nxt);
        u16* t = cur; cur = nxt; nxt = t;
    }
    mean_kernel<<<NG, 512, 0, stream>>>(cur, out);
}